// Round 5
// baseline (159.868 us; speedup 1.0000x reference)
//
#include <hip/hip_runtime.h>

#define BB 512
#define SS 512
#define TT 64
#define TSTRIDE 66   // transitions is (66,66)

typedef _Float16 h2 __attribute__((ext_vector_type(2)));

__device__ __forceinline__ float first_lane(float v) {
    return __int_as_float(__builtin_amdgcn_readfirstlane(__float_as_int(v)));
}
__device__ __forceinline__ unsigned pk_f16(float a, float b) {
    return __builtin_bit_cast(unsigned, __builtin_amdgcn_cvt_pkrtz(a, b));
}
__device__ __forceinline__ h2 as_h2(unsigned u) {
    return __builtin_bit_cast(h2, u);
}
#define FDOT2(a, b, c) __builtin_amdgcn_fdot2((a), (b), (c), false)

// One wave per batch. Lane j owns score[j]. E[i][j]=exp(tt[i][j]) lives in
// LDS, f16-packed: EQ[q][j] = 16B holding rows 8q..8q+7 of column j.
// R1-R4 lesson: the GCN scheduler targets max waves-per-eu (~8-10) and
// remats/spills any large register-resident table regardless of
// __launch_bounds__(,1). Defenses: (a) amdgpu_waves_per_eu(1,1) pins the
// occupancy target; (b) E in LDS so RA pressure is structurally tiny;
// (c) memory clobber in the loop stops LICM re-hoisting the LDS reads.
__global__ __launch_bounds__(64)
__attribute__((amdgpu_waves_per_eu(1, 1)))
void crf_fused_kernel(
    const float* __restrict__ emissions,   // [B,S,T]
    const int*   __restrict__ tags,        // [B,S]
    const float* __restrict__ mask,        // [B,S]
    const float* __restrict__ trans,       // [66,66]
    float* __restrict__ diff_out)          // [B] = logZ - gold
{
    __shared__ uint4 EQ[8][64];   // 8 KB

    const int b = blockIdx.x;
    const int j = threadIdx.x;   // 0..63
    const bool odd = (j & 1) != 0;

    const float* em = emissions + (size_t)b * SS * TT;
    const float* mk = mask + (size_t)b * SS;

    // ---- init E in LDS (low register pressure: one chunk at a time) ----
    #pragma unroll
    for (int q = 0; q < 8; ++q) {
        float x0 = __expf(trans[(8 * q + 0) * TSTRIDE + j]);
        float x1 = __expf(trans[(8 * q + 1) * TSTRIDE + j]);
        float x2 = __expf(trans[(8 * q + 2) * TSTRIDE + j]);
        float x3 = __expf(trans[(8 * q + 3) * TSTRIDE + j]);
        float x4 = __expf(trans[(8 * q + 4) * TSTRIDE + j]);
        float x5 = __expf(trans[(8 * q + 5) * TSTRIDE + j]);
        float x6 = __expf(trans[(8 * q + 6) * TSTRIDE + j]);
        float x7 = __expf(trans[(8 * q + 7) * TSTRIDE + j]);
        uint4 v;
        v.x = pk_f16(x0, x1);
        v.y = pk_f16(x2, x3);
        v.z = pk_f16(x4, x5);
        v.w = pk_f16(x6, x7);
        EQ[q][j] = v;
    }
    __syncthreads();

    // score0[j] = (em[0,j] + trans[j, start=64]) * mask[b,0]
    float score = (em[j] + trans[j * TSTRIDE + TT]) * mk[0];

    // rolling emission prefetch, depth 3 (branchless clamped index)
    float e1 = em[1 * TT + j];
    float e2 = em[2 * TT + j];
    float e3 = em[3 * TT + j];
    float mv1 = mk[1];

    for (int s = 1; s < SS; ++s) {
        asm volatile("" ::: "memory");   // keep EQ reads inside the loop

        // issue all 8 LDS chunk reads up front (latency overlaps exp/pack)
        uint4 c0 = EQ[0][j], c1 = EQ[1][j], c2 = EQ[2][j], c3 = EQ[3][j];
        uint4 c4 = EQ[4][j], c5 = EQ[5][j], c6 = EQ[6][j], c7 = EQ[7][j];

        float emit = e1;
        float mval = mv1;
        e1 = e2; e2 = e3;
        int pf = s + 3 < SS - 1 ? s + 3 : SS - 1;
        e3 = em[pf * TT + j];
        int pm = s + 1 < SS - 1 ? s + 1 : SS - 1;
        mv1 = mk[pm];

        // normalizer: first lane + margin keeps exp args in safe f16 range
        float m0c = first_lane(score) + 4.0f;
        float p   = __expf(score - m0c);

        // pack {p_even, p_odd} per lane-pair: DPP neighbor swap
        float pn = __int_as_float(
            __builtin_amdgcn_mov_dpp(__float_as_int(p), 0xB1, 0xF, 0xF, true));
        float lo = odd ? pn : p;
        float hi = odd ? p  : pn;
        int pki = (int)pk_f16(lo, hi);

        float a0 = 0.f, a1 = 0.f, a2 = 0.f, a3 = 0.f;
        // chunk q word w holds E rows {8q+2w, 8q+2w+1}; matching p pair is
        // readlane(pki, 8q+2w).
#define DOTC(C, Q) \
        a0 = FDOT2(as_h2((unsigned)__builtin_amdgcn_readlane(pki, 8*(Q)+0)), as_h2((C).x), a0); \
        a1 = FDOT2(as_h2((unsigned)__builtin_amdgcn_readlane(pki, 8*(Q)+2)), as_h2((C).y), a1); \
        a2 = FDOT2(as_h2((unsigned)__builtin_amdgcn_readlane(pki, 8*(Q)+4)), as_h2((C).z), a2); \
        a3 = FDOT2(as_h2((unsigned)__builtin_amdgcn_readlane(pki, 8*(Q)+6)), as_h2((C).w), a3);
        DOTC(c0, 0) DOTC(c1, 1) DOTC(c2, 2) DOTC(c3, 3)
        DOTC(c4, 4) DOTC(c5, 5) DOTC(c6, 6) DOTC(c7, 7)
#undef DOTC

        float sum = (a0 + a1) + (a2 + a3);
        score = m0c + __logf(sum) + emit * mval;
    }

    // + trans[stop=65, j], then exact wave logsumexp (f32)
    score += trans[65 * TSTRIDE + j];
    float m = score;
    #pragma unroll
    for (int off = 32; off; off >>= 1) m = fmaxf(m, __shfl_xor(m, off));
    float e = __expf(score - m);
    #pragma unroll
    for (int off = 32; off; off >>= 1) e += __shfl_xor(e, off);
    float zres = m + __logf(e);   // valid in lane 0

    // ---- gold path score (fused tail) ----
    const int* tg = tags + (size_t)b * SS;
    float acc  = 0.f;
    float msum = 0.f;
    for (int s = j; s < SS; s += 64) {
        float mm = mk[s];
        msum += mm;
        if (s > 0) {
            int curr = tg[s], prev = tg[s - 1];
            acc += (trans[curr * TSTRIDE + prev] + em[s * TT + curr]) * mm;
        } else {
            int t0 = tg[0];
            acc += (em[t0] + trans[t0 * TSTRIDE + TT]) * mm;
        }
    }
    #pragma unroll
    for (int off = 32; off; off >>= 1) {
        acc  += __shfl_xor(acc,  off);
        msum += __shfl_xor(msum, off);
    }
    if (j == 0) {
        int len  = (int)(msum + 0.5f);
        int last = tg[len - 1];
        acc += trans[65 * TSTRIDE + last];
        diff_out[b] = zres - acc;
    }
}

__global__ __launch_bounds__(256) void crf_final_kernel(
    const float* __restrict__ diff,
    float* __restrict__ out)
{
    __shared__ float sdata[4];
    int t = threadIdx.x;
    float v = 0.f;
    for (int i = t; i < BB; i += 256) v += diff[i];
    #pragma unroll
    for (int off = 32; off; off >>= 1) v += __shfl_xor(v, off);
    if ((t & 63) == 0) sdata[t >> 6] = v;
    __syncthreads();
    if (t == 0) out[0] = (sdata[0] + sdata[1] + sdata[2] + sdata[3]) * (1.0f / BB);
}

extern "C" void kernel_launch(void* const* d_in, const int* in_sizes, int n_in,
                              void* d_out, int out_size, void* d_ws, size_t ws_size,
                              hipStream_t stream) {
    const float* emissions = (const float*)d_in[0];
    const int*   tags      = (const int*)d_in[1];
    const float* mask      = (const float*)d_in[2];
    const float* trans     = (const float*)d_in[3];
    float* out  = (float*)d_out;
    float* diff = (float*)d_ws;

    crf_fused_kernel<<<BB, 64, 0, stream>>>(emissions, tags, mask, trans, diff);
    crf_final_kernel<<<1, 256, 0, stream>>>(diff, out);
}